// Round 1
// 23700.125 us; speedup vs baseline: 1.0286x; 1.0286x over previous
//
#include <hip/hip_runtime.h>
#include <cstdint>
#include <cstddef>

// ---------------------------------------------------------------------------
// Tacotron decoder, MI355X. Round 3: phase-count reduction.
// Theory: kernel is phase-serialization bound (95.6us/step vs ~15us VALU).
//  - GRU Wg + Wc(x-part) fused into one phase (Wc rows are contiguous:
//    x-rows first, h-rows second -> just offset split, no relayout).
//  - concat fills folded into reduce epilogues (each deletes a barrier).
//  - softmax without max-subtraction (|e| <= sum|v| ~ 10, exp safe in fp32):
//    deletes the 3-sync max reduction.
//  - weight_per: per-wave shuffle + 4 global atomics (deletes 3-sync reduce).
//  - energy loop unroll 16 (keysT is L3-resident, ~800cy latency).
// Phases/step: 28 -> 13. Syncs/step: ~44 -> 27.
// ---------------------------------------------------------------------------

#define TDEC   250
#define BATCH  128

#define ALPHA_OFF  ((size_t)12800000)        // 128*1250*80 floats
#define WP_OFF     ((size_t)45568000)

// ---- ws byte offsets ----
#define WS_WACC_B   ((size_t)0)
#define WS_WGT_B    ((size_t)4096)
#define WGT_ELEMS   1658880
#define WS_KEYS_B   (WS_WGT_B + (size_t)WGT_ELEMS * 2)
#define WS_ENC_B    (WS_KEYS_B + (size_t)33554432 * 2)

// ---- weight offsets (bf16 elems) ----
#define OFF_PRE_W1   0          // 80x256
#define OFF_PRE_W2   20480      // 256x128
#define OFF_ATT_WG   53248      // 640x512
#define OFF_ATT_WC   380928     // 640x256 (rows 0..383 = x-part)
#define OFF_ATT_WCH  479232     // = OFF_ATT_WC + 384*256 (rows 384..639, r*h part)
#define OFF_ATTN_WQ  544768     // 256x256
#define OFF_DECI_W   610304     // 512x256
#define OFF_DEC1_WG  741376     // 512x512
#define OFF_DEC1_WC  1003520    // 512x256 (rows 0..255 = x-part)
#define OFF_DEC1_WCH 1069056    // rows 256..511 (r*h part)
#define OFF_DEC2_WG  1134592    // 512x512
#define OFF_DEC2_WC  1396736    // 512x256
#define OFF_DEC2_WCH 1462272    // rows 256..511
#define OFF_OUT_WP   1527808    // 256x512 (padded from 256x400)

__device__ inline float bf2f(unsigned short u){
    return __uint_as_float(((unsigned int)u) << 16);
}
__device__ inline unsigned short f2bf(float f){
    unsigned int u = __float_as_uint(f);
    u = (u + 0x7fffu + ((u >> 16) & 1u)) >> 16;
    return (unsigned short)u;
}
__device__ inline float ftanh(float x){
    float e = __expf(2.f * x);
    return 1.f - 2.f * __builtin_amdgcn_rcpf(e + 1.f);
}
__device__ inline float fsig(float x){
    return __builtin_amdgcn_rcpf(1.f + __expf(-x));
}

// ---------------- bf16 GEMV partials: scratch[part][N] = x_part @ W_part ----
// No barriers inside; caller syncs and reduces.
template<int K, int N, int PARTS>
__device__ inline void gemv_part(const unsigned short* __restrict__ W,
                                 const float* __restrict__ x,
                                 float* __restrict__ scratch, int tid)
{
    constexpr int CH   = N / 8;
    constexpr int LG   = (CH == 16) ? 4 : (CH == 32) ? 5 : 6;
    constexpr int KCNT = K / PARTS;
    static_assert(KCNT * PARTS == K, "K must divide");
    static_assert(CH * PARTS <= 1024, "too many threads");
    const int chunk = tid & (CH - 1);
    const int part  = tid >> LG;
    if (PARTS == (1024 >> LG) || part < PARTS){
        const uint4* Wp = (const uint4*)W + (size_t)(part * KCNT) * (N / 8) + chunk;
        const float* xp = x + part * KCNT;
        float a0=0.f,a1=0.f,a2=0.f,a3=0.f,a4=0.f,a5=0.f,a6=0.f,a7=0.f;
        #pragma unroll 8
        for (int k = 0; k < KCNT; k++){
            uint4 w = Wp[(size_t)k * (N / 8)];
            float xv = xp[k];
            a0 = fmaf(__uint_as_float(w.x << 16),         xv, a0);
            a1 = fmaf(__uint_as_float(w.x & 0xffff0000u), xv, a1);
            a2 = fmaf(__uint_as_float(w.y << 16),         xv, a2);
            a3 = fmaf(__uint_as_float(w.y & 0xffff0000u), xv, a3);
            a4 = fmaf(__uint_as_float(w.z << 16),         xv, a4);
            a5 = fmaf(__uint_as_float(w.z & 0xffff0000u), xv, a5);
            a6 = fmaf(__uint_as_float(w.w << 16),         xv, a6);
            a7 = fmaf(__uint_as_float(w.w & 0xffff0000u), xv, a7);
        }
        float4* s4 = (float4*)(scratch + part * N + chunk * 8);
        s4[0] = float4{a0, a1, a2, a3};
        s4[1] = float4{a4, a5, a6, a7};
    }
}

template<int N, int PARTS>
__device__ inline float red_parts(const float* __restrict__ scratch, int n){
    float s = 0.f;
    #pragma unroll
    for (int p = 0; p < PARTS; p++) s += scratch[p * N + n];
    return s;
}

// ---------------- prep: fp32 -> bf16 conversions ----------------------------
__global__ void k_cvt_flat(const float* __restrict__ src, unsigned short* __restrict__ dst, int n){
    int i = blockIdx.x * 256 + threadIdx.x;
    if (i < n) dst[i] = f2bf(src[i]);
}
__global__ void k_cvt_pad(const float* __restrict__ src, unsigned short* __restrict__ dst){
    int i = blockIdx.x * 256 + threadIdx.x;   // i < 256*512
    int k = i >> 9, n = i & 511;
    dst[i] = (n < 400) ? f2bf(src[k * 400 + n]) : (unsigned short)0;
}

// ---------------- K1: keys_T[b][d][t] = bf16(enc @ Wk + bk) -----------------
__global__ __launch_bounds__(256) void k_keys(const float* __restrict__ enc,
                                              const float* __restrict__ Wk,
                                              const float* __restrict__ bk,
                                              unsigned short* __restrict__ keysT)
{
    __shared__ __align__(16) float Wt[64 * 256];   // [kk][d]
    __shared__ float At[64 * 64];                  // [r][kk]
    __shared__ unsigned short tileT[256 * 68];     // [d][t_loc], pad 68
    const int tid = threadIdx.x;
    const size_t row0 = (size_t)blockIdx.x * 64;
    const int dq = tid & 63;
    const int rg = tid >> 6;

    float4 acc[16];
    #pragma unroll
    for (int i = 0; i < 16; i++) acc[i] = float4{0.f, 0.f, 0.f, 0.f};

    for (int k0 = 0; k0 < 256; k0 += 64){
        __syncthreads();
        #pragma unroll
        for (int i = 0; i < 64; i++)
            Wt[i * 256 + tid] = Wk[(size_t)(k0 + i) * 256 + tid];
        #pragma unroll
        for (int i = 0; i < 16; i++){
            int idx = tid + i * 256;
            int r = idx >> 6, kk = idx & 63;
            At[idx] = enc[(row0 + r) * 256 + k0 + kk];
        }
        __syncthreads();
        for (int kk = 0; kk < 64; kk++){
            float4 w = ((const float4*)Wt)[kk * 64 + dq];
            #pragma unroll
            for (int rr = 0; rr < 16; rr++){
                float a = At[(rg * 16 + rr) * 64 + kk];
                acc[rr].x += a * w.x; acc[rr].y += a * w.y;
                acc[rr].z += a * w.z; acc[rr].w += a * w.w;
            }
        }
    }
    float4 bb = ((const float4*)bk)[dq];
    __syncthreads();
    #pragma unroll
    for (int rr = 0; rr < 16; rr++){
        int t_loc = rg * 16 + rr;
        #pragma unroll
        for (int c = 0; c < 4; c++){
            float val = (&acc[rr].x)[c] + (&bb.x)[c];
            int d = dq * 4 + c;
            tileT[d * 68 + t_loc] = f2bf(val);
        }
    }
    __syncthreads();
    const int b_ = (int)(row0 >> 10);
    const int t0 = (int)(row0 & 1023);
    #pragma unroll
    for (int i = 0; i < 16; i++){
        int flat = tid + i * 256;
        int d = flat >> 4, tq = flat & 15;
        ushort4 v = *(const ushort4*)&tileT[d * 68 + tq * 4];
        *(ushort4*)&keysT[(((size_t)(b_ * 256 + d)) << 10) + t0 + tq * 4] = v;
    }
}

// ---------------- K2: main recurrent kernel, block = batch row b ------------
struct KParams {
    const int *imask; const float *inp_att; const float *style_tok;
    const float *pre_b1, *pre_b2, *att_bg, *att_bc, *attn_bq, *attn_v;
    const float *deci_b, *dec1_bg, *dec1_bc, *dec2_bg, *dec2_bc, *out_b;
    const unsigned short *wgt;      // bf16 weight block
    const unsigned short *keysT;    // [128][256][1024] bf16
    const unsigned short *encb;     // [128][1024][256] bf16
    float *wacc; float *out;
};

__global__ __launch_bounds__(1024, 1) void k_main(KParams p)
{
    __shared__ __align__(16) float scr [8192];     // GEMV/attention partials
    __shared__ __align__(16) float scr2[8192];     // second partial buffer
    __shared__ float xa[640];                       // [ctx, p, h_att] (att GRU in)
    __shared__ float xg[512];                       // [x, h] (dec GRU in)
    __shared__ float xr[256];                       // r*h
    __shared__ float xd[512];                       // [h_att, wctx]
    __shared__ float g_l[512], cx_l[256];
    __shared__ float h_att[256], h1[256], h2[256];
    __shared__ float p1_l[256], dci[256], o1_l[256], o2_l[256];
    __shared__ float stylel[256], astylel[256], v_l[256], q_l[256];
    __shared__ float e_l[1024];
    __shared__ float last_o[80];
    __shared__ float red[16];

    const int tid = threadIdx.x;
    const int b   = blockIdx.x;
    const int mlen = p.imask[b];          // 1..1024
    const unsigned short* W = p.wgt;

    if (tid < 256){
        h_att[tid] = 0.f; h1[tid] = 0.f; h2[tid] = 0.f;
        float s = 0.f;
        #pragma unroll
        for (int k = 0; k < 10; k++) s += p.inp_att[b * 10 + k] * p.style_tok[k * 256 + tid];
        stylel[tid] = s; astylel[tid] = fabsf(s);
        v_l[tid] = p.attn_v[tid];
        xa[tid] = 0.f;            // ctx = 0
        xa[384 + tid] = 0.f;      // h_att = 0
    }
    if (tid < 80) last_o[tid] = 0.f;
    __syncthreads();

    for (int s = 0; s < TDEC; s++){
        // ---- P1: prenet1 (80 -> 256, relu) ----
        gemv_part<80, 256, 16>(W + OFF_PRE_W1, last_o, scr, tid);
        __syncthreads();
        if (tid < 256)
            p1_l[tid] = fmaxf(p.pre_b1[tid] + red_parts<256,16>(scr, tid), 0.f);
        __syncthreads();

        // ---- P2: prenet2 (256 -> 128, relu) -> xa[256..383] ----
        gemv_part<256, 128, 64>(W + OFF_PRE_W2, p1_l, scr, tid);
        __syncthreads();
        if (tid < 128)
            xa[256 + tid] = fmaxf(p.pre_b2[tid] + red_parts<128,64>(scr, tid), 0.f);
        __syncthreads();

        // ---- P3: att GRU phase A: g = sig(xa@Wg), cx = bc + xa[0:384]@Wc_x
        gemv_part<640, 512, 16>(W + OFF_ATT_WG, xa, scr,  tid);
        gemv_part<384, 256, 32>(W + OFF_ATT_WC, xa, scr2, tid);
        __syncthreads();
        if (tid < 512){
            float g = fsig(p.att_bg[tid] + red_parts<512,16>(scr, tid));
            g_l[tid] = g;
            if (tid < 256) xr[tid] = g * h_att[tid];        // r*h
        } else if (tid < 768){
            int n = tid - 512;
            cx_l[n] = p.att_bc[n] + red_parts<256,32>(scr2, n);
        }
        __syncthreads();

        // ---- P4: att GRU phase B: c = tanh(cx + (r*h)@Wc_h); h update ----
        gemv_part<256, 256, 32>(W + OFF_ATT_WCH, xr, scr, tid);
        __syncthreads();
        if (tid < 256){
            float c = ftanh(cx_l[tid] + red_parts<256,32>(scr, tid));
            float u = g_l[256 + tid];
            float h = u * h_att[tid] + (1.f - u) * c;
            h_att[tid] = h;
            xa[384 + tid] = h;     // for next step's P3
            xd[tid] = h;           // for P8 (deci)
        }
        __syncthreads();

        // ---- P5: q = h_att @ Wq + bq ----
        gemv_part<256, 256, 32>(W + OFF_ATTN_WQ, h_att, scr, tid);
        __syncthreads();
        if (tid < 256) q_l[tid] = p.attn_bq[tid] + red_parts<256,32>(scr, tid);
        __syncthreads();

        // ---- P6: energy e[t] = sum_d tanh(keysT[d][t]+q[d])*v[d]; softmax
        // (max-free: |e| <= sum|v| ~ 10, exp safe in fp32)
        {
            const int tc   = tid & 127;
            const int part = tid >> 7;
            float acc0=0.f,acc1=0.f,acc2=0.f,acc3=0.f,acc4=0.f,acc5=0.f,acc6=0.f,acc7=0.f;
            if (tc * 8 < mlen){
                const unsigned short* kp = p.keysT + (((size_t)b) << 18)
                                         + ((size_t)(part * 32) << 10) + tc * 8;
                #pragma unroll 16
                for (int dd = 0; dd < 32; dd++){
                    uint4 kv = *(const uint4*)(kp + ((size_t)dd << 10));
                    int d = part * 32 + dd;
                    float qd = q_l[d], vd = v_l[d];
                    acc0 = fmaf(ftanh(__uint_as_float(kv.x << 16)         + qd), vd, acc0);
                    acc1 = fmaf(ftanh(__uint_as_float(kv.x & 0xffff0000u) + qd), vd, acc1);
                    acc2 = fmaf(ftanh(__uint_as_float(kv.y << 16)         + qd), vd, acc2);
                    acc3 = fmaf(ftanh(__uint_as_float(kv.y & 0xffff0000u) + qd), vd, acc3);
                    acc4 = fmaf(ftanh(__uint_as_float(kv.z << 16)         + qd), vd, acc4);
                    acc5 = fmaf(ftanh(__uint_as_float(kv.z & 0xffff0000u) + qd), vd, acc5);
                    acc6 = fmaf(ftanh(__uint_as_float(kv.w << 16)         + qd), vd, acc6);
                    acc7 = fmaf(ftanh(__uint_as_float(kv.w & 0xffff0000u) + qd), vd, acc7);
                }
            }
            float4* s4 = (float4*)(scr + part * 1024 + tc * 8);
            s4[0] = float4{acc0, acc1, acc2, acc3};
            s4[1] = float4{acc4, acc5, acc6, acc7};
        }
        __syncthreads();
        float av = 0.f;
        if (tid < mlen){
            float s8 = 0.f;
            #pragma unroll
            for (int pp = 0; pp < 8; pp++) s8 += scr[pp * 1024 + tid];
            av = __expf(s8);
        }
        {   // block sum: per-wave shuffle -> 16 LDS -> broadcast sum
            float ws = av;
            #pragma unroll
            for (int off = 32; off; off >>= 1) ws += __shfl_xor(ws, off, 64);
            if ((tid & 63) == 0) red[tid >> 6] = ws;
        }
        __syncthreads();
        {
            float tot = 0.f;
            #pragma unroll
            for (int i = 0; i < 16; i++) tot += red[i];
            float alpha = av * __builtin_amdgcn_rcpf(tot);
            e_l[tid] = alpha;
            __builtin_nontemporal_store(alpha,
                &p.out[ALPHA_OFF + (size_t)s * 131072 + ((size_t)b << 10) + tid]);
        }
        __syncthreads();

        // ---- P7: context ctx[d] = sum_t alpha[t]*enc[t][d]; fills xa/xd, wp
        {
            const int dc = tid & 31;
            const int tp = tid >> 5;
            float acc0=0.f,acc1=0.f,acc2=0.f,acc3=0.f,acc4=0.f,acc5=0.f,acc6=0.f,acc7=0.f;
            const unsigned short* er = p.encb + (((size_t)b) << 18) + dc * 8;
            #pragma unroll 8
            for (int t = tp; t < mlen; t += 32){
                uint4 ev4 = *(const uint4*)(er + ((size_t)t << 8));
                float al = e_l[t];
                acc0 = fmaf(al, __uint_as_float(ev4.x << 16),         acc0);
                acc1 = fmaf(al, __uint_as_float(ev4.x & 0xffff0000u), acc1);
                acc2 = fmaf(al, __uint_as_float(ev4.y << 16),         acc2);
                acc3 = fmaf(al, __uint_as_float(ev4.y & 0xffff0000u), acc3);
                acc4 = fmaf(al, __uint_as_float(ev4.z << 16),         acc4);
                acc5 = fmaf(al, __uint_as_float(ev4.z & 0xffff0000u), acc5);
                acc6 = fmaf(al, __uint_as_float(ev4.w << 16),         acc6);
                acc7 = fmaf(al, __uint_as_float(ev4.w & 0xffff0000u), acc7);
            }
            float4* s4 = (float4*)(scr + tp * 256 + dc * 8);
            s4[0] = float4{acc0, acc1, acc2, acc3};
            s4[1] = float4{acc4, acc5, acc6, acc7};
        }
        __syncthreads();
        if (tid < 256){
            float cs = red_parts<256,32>(scr, tid);
            xa[tid] = cs;                        // ctx for next step's P3
            xd[256 + tid] = cs + stylel[tid];    // wctx for P8
            float wpv = astylel[tid] * __builtin_amdgcn_rcpf(fabsf(cs) + astylel[tid]);
            #pragma unroll
            for (int off = 32; off; off >>= 1) wpv += __shfl_xor(wpv, off, 64);
            if ((tid & 63) == 0) atomicAdd(&p.wacc[s], wpv);
        }
        __syncthreads();

        // ---- P8: dec_in = [h_att, wctx] @ deci_W + b ----
        gemv_part<512, 256, 32>(W + OFF_DECI_W, xd, scr, tid);
        __syncthreads();
        if (tid < 256){
            float d = p.deci_b[tid] + red_parts<256,32>(scr, tid);
            dci[tid] = d;
            xg[tid] = d; xg[256 + tid] = h1[tid];
        }
        __syncthreads();

        // ---- P9: dec1 phase A ----
        gemv_part<512, 512, 16>(W + OFF_DEC1_WG, xg, scr,  tid);
        gemv_part<256, 256, 32>(W + OFF_DEC1_WC, xg, scr2, tid);   // x-part only
        __syncthreads();
        if (tid < 512){
            float g = fsig(p.dec1_bg[tid] + red_parts<512,16>(scr, tid));
            g_l[tid] = g;
            if (tid < 256) xr[tid] = g * h1[tid];
        } else if (tid < 768){
            int n = tid - 512;
            cx_l[n] = p.dec1_bc[n] + red_parts<256,32>(scr2, n);
        }
        __syncthreads();

        // ---- P10: dec1 phase B ----
        gemv_part<256, 256, 32>(W + OFF_DEC1_WCH, xr, scr, tid);
        __syncthreads();
        if (tid < 256){
            float c = ftanh(cx_l[tid] + red_parts<256,32>(scr, tid));
            float u = g_l[256 + tid];
            float hn = u * h1[tid] + (1.f - u) * c;
            h1[tid] = hn;
            float o1 = hn + dci[tid];
            o1_l[tid] = o1;
            xg[tid] = o1; xg[256 + tid] = h2[tid];
        }
        __syncthreads();

        // ---- P11: dec2 phase A ----
        gemv_part<512, 512, 16>(W + OFF_DEC2_WG, xg, scr,  tid);
        gemv_part<256, 256, 32>(W + OFF_DEC2_WC, xg, scr2, tid);
        __syncthreads();
        if (tid < 512){
            float g = fsig(p.dec2_bg[tid] + red_parts<512,16>(scr, tid));
            g_l[tid] = g;
            if (tid < 256) xr[tid] = g * h2[tid];
        } else if (tid < 768){
            int n = tid - 512;
            cx_l[n] = p.dec2_bc[n] + red_parts<256,32>(scr2, n);
        }
        __syncthreads();

        // ---- P12: dec2 phase B ----
        gemv_part<256, 256, 32>(W + OFF_DEC2_WCH, xr, scr, tid);
        __syncthreads();
        if (tid < 256){
            float c = ftanh(cx_l[tid] + red_parts<256,32>(scr, tid));
            float u = g_l[256 + tid];
            float hn = u * h2[tid] + (1.f - u) * c;
            h2[tid] = hn;
            o2_l[tid] = hn + o1_l[tid];
        }
        __syncthreads();

        // ---- P13: output dense (256 -> 400 via padded 512) ----
        gemv_part<256, 512, 16>(W + OFF_OUT_WP, o2_l, scr, tid);
        __syncthreads();
        if (tid < 400){
            float val = p.out_b[tid] + red_parts<512,16>(scr, tid);
            __builtin_nontemporal_store(val,
                &p.out[(size_t)b * 100000 + (size_t)s * 400 + tid]);
            if (tid >= 320) last_o[tid - 320] = val;
        }
        __syncthreads();
    }
}

// ---------------- K3: finalize weight_pers ----------------------------------
__global__ void k_final(const float* __restrict__ wacc, float* __restrict__ out)
{
    int i = threadIdx.x;
    if (i < TDEC) out[WP_OFF + i] = wacc[i] * (1.0f / 32768.0f);
}

// ---------------------------------------------------------------------------
extern "C" void kernel_launch(void* const* d_in, const int* in_sizes, int n_in,
                              void* d_out, int out_size, void* d_ws, size_t ws_size,
                              hipStream_t stream)
{
    const float* enc        = (const float*)d_in[0];
    const int*   imask      = (const int*)  d_in[1];
    const float* inp_att    = (const float*)d_in[2];
    const float* style_tok  = (const float*)d_in[3];
    const float* pre_W1     = (const float*)d_in[4];
    const float* pre_b1     = (const float*)d_in[5];
    const float* pre_W2     = (const float*)d_in[6];
    const float* pre_b2     = (const float*)d_in[7];
    const float* att_Wg     = (const float*)d_in[8];
    const float* att_bg     = (const float*)d_in[9];
    const float* att_Wc     = (const float*)d_in[10];
    const float* att_bc     = (const float*)d_in[11];
    const float* attn_Wk    = (const float*)d_in[12];
    const float* attn_bk    = (const float*)d_in[13];
    const float* attn_Wq    = (const float*)d_in[14];
    const float* attn_bq    = (const float*)d_in[15];
    const float* attn_v     = (const float*)d_in[16];
    const float* deci_W     = (const float*)d_in[17];
    const float* deci_b     = (const float*)d_in[18];
    const float* dec1_Wg    = (const float*)d_in[19];
    const float* dec1_bg    = (const float*)d_in[20];
    const float* dec1_Wc    = (const float*)d_in[21];
    const float* dec1_bc    = (const float*)d_in[22];
    const float* dec2_Wg    = (const float*)d_in[23];
    const float* dec2_bg    = (const float*)d_in[24];
    const float* dec2_Wc    = (const float*)d_in[25];
    const float* dec2_bc    = (const float*)d_in[26];
    const float* out_W      = (const float*)d_in[27];
    const float* out_b      = (const float*)d_in[28];

    float*          wacc  = (float*)((char*)d_ws + WS_WACC_B);
    unsigned short* wgt   = (unsigned short*)((char*)d_ws + WS_WGT_B);
    unsigned short* keysT = (unsigned short*)((char*)d_ws + WS_KEYS_B);
    unsigned short* encb  = (unsigned short*)((char*)d_ws + WS_ENC_B);
    float* out = (float*)d_out;

    hipMemsetAsync(d_ws, 0, 1024, stream);

    // ---- weight conversions (bf16) ----
    auto cvt = [&](const float* src, size_t off, int n){
        k_cvt_flat<<<(n + 255) / 256, 256, 0, stream>>>(src, wgt + off, n);
    };
    cvt(pre_W1,  OFF_PRE_W1,   80 * 256);
    cvt(pre_W2,  OFF_PRE_W2,  256 * 128);
    cvt(att_Wg,  OFF_ATT_WG,  640 * 512);
    cvt(att_Wc,  OFF_ATT_WC,  640 * 256);
    cvt(attn_Wq, OFF_ATTN_WQ, 256 * 256);
    cvt(deci_W,  OFF_DECI_W,  512 * 256);
    cvt(dec1_Wg, OFF_DEC1_WG, 512 * 512);
    cvt(dec1_Wc, OFF_DEC1_WC, 512 * 256);
    cvt(dec2_Wg, OFF_DEC2_WG, 512 * 512);
    cvt(dec2_Wc, OFF_DEC2_WC, 512 * 256);
    k_cvt_pad<<<(256 * 512) / 256, 256, 0, stream>>>(out_W, wgt + OFF_OUT_WP);

    // ---- enc -> bf16 ----
    k_cvt_flat<<<(33554432 + 255) / 256, 256, 0, stream>>>(enc, encb, 33554432);

    // ---- keys (transposed bf16) ----
    k_keys<<<2048, 256, 0, stream>>>(enc, attn_Wk, attn_bk, keysT);

    KParams kp{imask, inp_att, style_tok,
               pre_b1, pre_b2, att_bg, att_bc, attn_bq, attn_v,
               deci_b, dec1_bg, dec1_bc, dec2_bg, dec2_bc, out_b,
               wgt, keysT, encb, wacc, out};
    k_main<<<BATCH, 1024, 0, stream>>>(kp);

    k_final<<<1, 256, 0, stream>>>(wacc, out);
}